// Round 1
// baseline (1795.729 us; speedup 1.0000x reference)
//
#include <hip/hip_runtime.h>

// ---------------------------------------------------------------------------
// TextGraphSAGE: 2-layer SAGEConv (mean aggr), N=50000, D=768, H=128, C=4,
// E=800000.  Key restructure: project BEFORE aggregating (mean commutes with
// the linear map), so the edge gather moves 128 floats/edge, not 768.
// ---------------------------------------------------------------------------

// ---- fp32 tiled GEMM:  C[M][N] = A[M][K] * B[N][K]^T  (both row-major, NT)
template<int BM, int BN, int BK>
__global__ __launch_bounds__(256)
void gemm_nt(const float* __restrict__ A, const float* __restrict__ B,
             float* __restrict__ C, int M, int N, int K)
{
    static_assert(BM == 64 && BN == 64 && BK == 32, "tile fixed");
    __shared__ float As[BK][BM + 4];   // transposed tiles, +4 keeps 16B align
    __shared__ float Bs[BK][BN + 4];
    const int bm = blockIdx.x * BM;
    const int bn = blockIdx.y * BN;
    const int tid = threadIdx.x;
    const int tx = tid & 15;    // N-dim 0..15
    const int ty = tid >> 4;    // M-dim 0..15

    float acc[4][4] = {};

    for (int k0 = 0; k0 < K; k0 += BK) {
        #pragma unroll
        for (int it = 0; it < 2; ++it) {            // 2048 floats = 512 float4
            int v   = tid + it * 256;
            int row = v >> 3;                        // 8 float4 per 32-f row
            int kc  = (v & 7) << 2;
            float4 a4 = make_float4(0.f, 0.f, 0.f, 0.f);
            if (bm + row < M)
                a4 = *(const float4*)(A + (size_t)(bm + row) * K + (k0 + kc));
            As[kc + 0][row] = a4.x; As[kc + 1][row] = a4.y;
            As[kc + 2][row] = a4.z; As[kc + 3][row] = a4.w;
            float4 b4 = make_float4(0.f, 0.f, 0.f, 0.f);
            if (bn + row < N)
                b4 = *(const float4*)(B + (size_t)(bn + row) * K + (k0 + kc));
            Bs[kc + 0][row] = b4.x; Bs[kc + 1][row] = b4.y;
            Bs[kc + 2][row] = b4.z; Bs[kc + 3][row] = b4.w;
        }
        __syncthreads();
        #pragma unroll
        for (int kk = 0; kk < BK; ++kk) {
            float4 av = *(const float4*)&As[kk][ty << 2];
            float4 bv = *(const float4*)&Bs[kk][tx << 2];
            float a[4] = {av.x, av.y, av.z, av.w};
            float b[4] = {bv.x, bv.y, bv.z, bv.w};
            #pragma unroll
            for (int i = 0; i < 4; ++i)
                #pragma unroll
                for (int j = 0; j < 4; ++j)
                    acc[i][j] = fmaf(a[i], b[j], acc[i][j]);
        }
        __syncthreads();
    }

    #pragma unroll
    for (int i = 0; i < 4; ++i) {
        int row = bm + (ty << 2) + i;
        if (row >= M) continue;
        #pragma unroll
        for (int j = 0; j < 4; ++j) {
            int col = bn + (tx << 2) + j;
            if (col < N) C[(size_t)row * N + col] = acc[i][j];
        }
    }
}

// ---- layer-1 edge aggregation: agg1[dst] += p[src] (128 f32), deg[dst] += 1
// 32 lanes per edge, each lane owns 4 contiguous features (float4 gather).
__global__ __launch_bounds__(256)
void edge_agg1(const int* __restrict__ ei, const float* __restrict__ p,
               float* __restrict__ agg, float* __restrict__ deg, int E)
{
    int t = blockIdx.x * 256 + threadIdx.x;
    int e = t >> 5;
    int lane = t & 31;
    if (e >= E) return;
    int src = ei[e];
    int dst = ei[E + e];
    float4 v = *(const float4*)(p + (size_t)src * 128 + lane * 4);
    float* ap = agg + (size_t)dst * 128 + lane * 4;
    atomicAdd(ap + 0, v.x);
    atomicAdd(ap + 1, v.y);
    atomicAdd(ap + 2, v.z);
    atomicAdd(ap + 3, v.w);
    if (lane == 0) atomicAdd(deg + dst, 1.0f);
}

// ---- h = relu(agg1/deg + b1 + q)
__global__ __launch_bounds__(256)
void finish1(const float* __restrict__ agg, const float* __restrict__ deg,
             const float* __restrict__ q, const float* __restrict__ b1,
             float* __restrict__ h, int N)
{
    int i = blockIdx.x * 256 + threadIdx.x;
    if (i >= N * 128) return;
    int n = i >> 7, f = i & 127;
    float d = fmaxf(deg[n], 1.0f);
    float v = agg[i] / d + b1[f] + q[i];
    h[i] = fmaxf(v, 0.0f);
}

// ---- layer-2 projection: r = h@W2l^T, s = h@W2r^T  (one wave per node)
__global__ __launch_bounds__(256)
void proj2(const float* __restrict__ h, const float* __restrict__ W2l,
           const float* __restrict__ W2r, float* __restrict__ r,
           float* __restrict__ s, int N)
{
    __shared__ float Wl[512], Wr[512];
    for (int i = threadIdx.x; i < 512; i += 256) {
        Wl[i] = W2l[i];
        Wr[i] = W2r[i];
    }
    __syncthreads();
    int wid  = threadIdx.x >> 6;
    int lane = threadIdx.x & 63;
    int n = blockIdx.x * 4 + wid;
    if (n >= N) return;
    float2 hv = *(const float2*)(h + (size_t)n * 128 + lane * 2);
    #pragma unroll
    for (int o = 0; o < 4; ++o) {
        float pl = hv.x * Wl[o * 128 + lane * 2] + hv.y * Wl[o * 128 + lane * 2 + 1];
        float pr = hv.x * Wr[o * 128 + lane * 2] + hv.y * Wr[o * 128 + lane * 2 + 1];
        #pragma unroll
        for (int off = 32; off; off >>= 1) {
            pl += __shfl_down(pl, off);
            pr += __shfl_down(pr, off);
        }
        if (lane == 0) {
            r[(size_t)n * 4 + o] = pl;
            s[(size_t)n * 4 + o] = pr;
        }
    }
}

// ---- layer-2 edge aggregation: agg2[dst] += r[src] (4 f32)
__global__ __launch_bounds__(256)
void edge_agg2(const int* __restrict__ ei, const float* __restrict__ r,
               float* __restrict__ agg2, int E)
{
    int t = blockIdx.x * 256 + threadIdx.x;
    int e = t >> 2;
    int c = t & 3;
    if (e >= E) return;
    int src = ei[e];
    int dst = ei[E + e];
    atomicAdd(agg2 + (size_t)dst * 4 + c, r[(size_t)src * 4 + c]);
}

// ---- out = agg2/deg + b2 + s
__global__ __launch_bounds__(256)
void finish2(const float* __restrict__ agg2, const float* __restrict__ deg,
             const float* __restrict__ s, const float* __restrict__ b2,
             float* __restrict__ out, int N)
{
    int i = blockIdx.x * 256 + threadIdx.x;
    if (i >= N * 4) return;
    int n = i >> 2, c = i & 3;
    out[i] = agg2[i] / fmaxf(deg[n], 1.0f) + b2[c] + s[i];
}

extern "C" void kernel_launch(void* const* d_in, const int* in_sizes, int n_in,
                              void* d_out, int out_size, void* d_ws, size_t ws_size,
                              hipStream_t stream)
{
    const float* x   = (const float*)d_in[0];
    const int*   ei  = (const int*)d_in[1];
    const float* W1l = (const float*)d_in[2];
    const float* b1l = (const float*)d_in[3];
    const float* W1r = (const float*)d_in[4];
    const float* W2l = (const float*)d_in[5];
    const float* b2l = (const float*)d_in[6];
    const float* W2r = (const float*)d_in[7];
    float* out = (float*)d_out;

    const int N = in_sizes[0] / 768;   // 50000
    const int E = in_sizes[1] / 2;     // 800000

    char* ws = (char*)d_ws;
    size_t off = 0;
    auto alloc = [&](size_t bytes) -> void* {
        void* pp = ws + off;
        off += (bytes + 255) & ~(size_t)255;
        return pp;
    };
    float* p    = (float*)alloc((size_t)N * 128 * 4);
    float* q    = (float*)alloc((size_t)N * 128 * 4);
    float* h    = (float*)alloc((size_t)N * 128 * 4);
    float* agg1 = (float*)alloc((size_t)N * 128 * 4);
    float* r    = (float*)alloc((size_t)N * 4 * 4);
    float* s    = (float*)alloc((size_t)N * 4 * 4);
    float* agg2 = (float*)alloc((size_t)N * 4 * 4);
    float* deg  = (float*)alloc((size_t)N * 4);

    hipMemsetAsync(agg1, 0, (size_t)N * 128 * 4, stream);
    hipMemsetAsync(agg2, 0, (size_t)N * 4 * 4, stream);
    hipMemsetAsync(deg,  0, (size_t)N * 4, stream);

    // layer 1 projections: p = x@W1l^T, q = x@W1r^T   (M=N, N=128, K=768)
    dim3 g1((N + 63) / 64, 128 / 64);
    gemm_nt<64, 64, 32><<<g1, 256, 0, stream>>>(x, W1l, p, N, 128, 768);
    gemm_nt<64, 64, 32><<<g1, 256, 0, stream>>>(x, W1r, q, N, 128, 768);

    // aggregate projected neighbors + degree
    edge_agg1<<<(E * 32 + 255) / 256, 256, 0, stream>>>(ei, p, agg1, deg, E);

    // h = relu(agg1/deg + b1 + q)
    finish1<<<(N * 128 + 255) / 256, 256, 0, stream>>>(agg1, deg, q, b1l, h, N);

    // layer 2 projections (tiny GEMMs, wave per node)
    proj2<<<(N + 3) / 4, 256, 0, stream>>>(h, W2l, W2r, r, s, N);

    // aggregate layer-2 neighbors
    edge_agg2<<<(E * 4 + 255) / 256, 256, 0, stream>>>(ei, r, agg2, E);

    // out = agg2/deg + b2 + s
    finish2<<<(N * 4 + 255) / 256, 256, 0, stream>>>(agg2, deg, s, b2l, out, N);
}

// Round 2
// 623.371 us; speedup vs baseline: 2.8807x; 2.8807x over previous
//
#include <hip/hip_runtime.h>

// ---------------------------------------------------------------------------
// TextGraphSAGE: 2-layer SAGEConv (mean aggr), N=50000, D=768, H=128, C=4,
// E=800000.
//  - project BEFORE aggregating (mean commutes with linear map)
//  - CSR gather instead of scatter atomics (round-1 profile: edge_agg1 was
//    77% of runtime, bound on 102M device-scope float atomics)
// ---------------------------------------------------------------------------

// ---- fp32 tiled GEMM:  C[M][N] = A[M][K] * B[N][K]^T  (both row-major, NT)
template<int BM, int BN, int BK>
__global__ __launch_bounds__(256)
void gemm_nt(const float* __restrict__ A, const float* __restrict__ B,
             float* __restrict__ C, int M, int N, int K)
{
    static_assert(BM == 64 && BN == 64 && BK == 32, "tile fixed");
    __shared__ float As[BK][BM + 4];
    __shared__ float Bs[BK][BN + 4];
    const int bm = blockIdx.x * BM;
    const int bn = blockIdx.y * BN;
    const int tid = threadIdx.x;
    const int tx = tid & 15;
    const int ty = tid >> 4;

    float acc[4][4] = {};

    for (int k0 = 0; k0 < K; k0 += BK) {
        #pragma unroll
        for (int it = 0; it < 2; ++it) {
            int v   = tid + it * 256;
            int row = v >> 3;
            int kc  = (v & 7) << 2;
            float4 a4 = make_float4(0.f, 0.f, 0.f, 0.f);
            if (bm + row < M)
                a4 = *(const float4*)(A + (size_t)(bm + row) * K + (k0 + kc));
            As[kc + 0][row] = a4.x; As[kc + 1][row] = a4.y;
            As[kc + 2][row] = a4.z; As[kc + 3][row] = a4.w;
            float4 b4 = make_float4(0.f, 0.f, 0.f, 0.f);
            if (bn + row < N)
                b4 = *(const float4*)(B + (size_t)(bn + row) * K + (k0 + kc));
            Bs[kc + 0][row] = b4.x; Bs[kc + 1][row] = b4.y;
            Bs[kc + 2][row] = b4.z; Bs[kc + 3][row] = b4.w;
        }
        __syncthreads();
        #pragma unroll
        for (int kk = 0; kk < BK; ++kk) {
            float4 av = *(const float4*)&As[kk][ty << 2];
            float4 bv = *(const float4*)&Bs[kk][tx << 2];
            float a[4] = {av.x, av.y, av.z, av.w};
            float b[4] = {bv.x, bv.y, bv.z, bv.w};
            #pragma unroll
            for (int i = 0; i < 4; ++i)
                #pragma unroll
                for (int j = 0; j < 4; ++j)
                    acc[i][j] = fmaf(a[i], b[j], acc[i][j]);
        }
        __syncthreads();
    }

    #pragma unroll
    for (int i = 0; i < 4; ++i) {
        int row = bm + (ty << 2) + i;
        if (row >= M) continue;
        #pragma unroll
        for (int j = 0; j < 4; ++j) {
            int col = bn + (tx << 2) + j;
            if (col < N) C[(size_t)row * N + col] = acc[i][j];
        }
    }
}

// ---- CSR build step 1: degree histogram (int atomics, 800K ops)
__global__ __launch_bounds__(256)
void csr_count(const int* __restrict__ ei, int* __restrict__ deg, int E)
{
    int e = blockIdx.x * 256 + threadIdx.x;
    if (e >= E) return;
    atomicAdd(&deg[ei[E + e]], 1);
}

// ---- CSR build step 2: exclusive scan of deg -> row_ptr (and cursor copy).
// Single block of 1024 threads, sequential 1024-chunks, Hillis-Steele in LDS.
__global__ __launch_bounds__(1024)
void scan_deg(const int* __restrict__ deg, int* __restrict__ row_ptr,
              int* __restrict__ cursor, int N)
{
    __shared__ int buf[1024];
    int carry = 0;
    for (int base = 0; base < N; base += 1024) {
        int i = base + (int)threadIdx.x;
        int v = (i < N) ? deg[i] : 0;
        buf[threadIdx.x] = v;
        __syncthreads();
        #pragma unroll
        for (int off = 1; off < 1024; off <<= 1) {
            int t = (threadIdx.x >= (unsigned)off) ? buf[threadIdx.x - off] : 0;
            __syncthreads();
            buf[threadIdx.x] += t;
            __syncthreads();
        }
        int excl = buf[threadIdx.x] - v + carry;
        if (i < N) { row_ptr[i] = excl; cursor[i] = excl; }
        carry += buf[1023];          // block-uniform chunk total
        __syncthreads();             // protect buf before next chunk
    }
    if (threadIdx.x == 0) row_ptr[N] = carry;
}

// ---- CSR build step 3: scatter src ids into per-dst slots
__global__ __launch_bounds__(256)
void csr_fill(const int* __restrict__ ei, int* __restrict__ cursor,
              int* __restrict__ csr_src, int E)
{
    int e = blockIdx.x * 256 + threadIdx.x;
    if (e >= E) return;
    int src = ei[e];
    int dst = ei[E + e];
    int pos = atomicAdd(&cursor[dst], 1);
    csr_src[pos] = src;
}

// ---- layer 1: h[n] = relu(mean_{src in N(n)} p[src] + b1 + q[n])
// one wave per node; lane owns 2 features; coalesced 512B row reads of p
__global__ __launch_bounds__(256)
void sage1_gather(const int* __restrict__ row_ptr, const int* __restrict__ csr_src,
                  const float* __restrict__ p, const float* __restrict__ q,
                  const float* __restrict__ b1, float* __restrict__ h, int N)
{
    int wid  = threadIdx.x >> 6;
    int lane = threadIdx.x & 63;
    int n = blockIdx.x * 4 + wid;
    if (n >= N) return;
    int beg = row_ptr[n], end = row_ptr[n + 1];
    float ax = 0.f, ay = 0.f;
    for (int e = beg; e < end; ++e) {
        int src = csr_src[e];
        float2 v = *(const float2*)(p + (size_t)src * 128 + lane * 2);
        ax += v.x; ay += v.y;
    }
    float inv = 1.0f / fmaxf((float)(end - beg), 1.0f);
    size_t o = (size_t)n * 128 + lane * 2;
    float2 qv = *(const float2*)(q + o);
    float2 bv = *(const float2*)(b1 + lane * 2);
    float2 hv;
    hv.x = fmaxf(ax * inv + bv.x + qv.x, 0.f);
    hv.y = fmaxf(ay * inv + bv.y + qv.y, 0.f);
    *(float2*)(h + o) = hv;
}

// ---- layer-2 projection: r = h@W2l^T, s = h@W2r^T  (one wave per node)
__global__ __launch_bounds__(256)
void proj2(const float* __restrict__ h, const float* __restrict__ W2l,
           const float* __restrict__ W2r, float* __restrict__ r,
           float* __restrict__ s, int N)
{
    __shared__ float Wl[512], Wr[512];
    for (int i = threadIdx.x; i < 512; i += 256) {
        Wl[i] = W2l[i];
        Wr[i] = W2r[i];
    }
    __syncthreads();
    int wid  = threadIdx.x >> 6;
    int lane = threadIdx.x & 63;
    int n = blockIdx.x * 4 + wid;
    if (n >= N) return;
    float2 hv = *(const float2*)(h + (size_t)n * 128 + lane * 2);
    #pragma unroll
    for (int o = 0; o < 4; ++o) {
        float pl = hv.x * Wl[o * 128 + lane * 2] + hv.y * Wl[o * 128 + lane * 2 + 1];
        float pr = hv.x * Wr[o * 128 + lane * 2] + hv.y * Wr[o * 128 + lane * 2 + 1];
        #pragma unroll
        for (int off = 32; off; off >>= 1) {
            pl += __shfl_down(pl, off);
            pr += __shfl_down(pr, off);
        }
        if (lane == 0) {
            r[(size_t)n * 4 + o] = pl;
            s[(size_t)n * 4 + o] = pr;
        }
    }
}

// ---- layer 2: out[n] = mean_{src} r[src] + b2 + s[n]
// one thread per (node, channel); r is 800KB -> L2-resident
__global__ __launch_bounds__(256)
void sage2_gather(const int* __restrict__ row_ptr, const int* __restrict__ csr_src,
                  const float* __restrict__ r, const float* __restrict__ s,
                  const float* __restrict__ b2, float* __restrict__ out, int N)
{
    int t = blockIdx.x * 256 + threadIdx.x;
    if (t >= N * 4) return;
    int n = t >> 2, c = t & 3;
    int beg = row_ptr[n], end = row_ptr[n + 1];
    float acc = 0.f;
    for (int e = beg; e < end; ++e)
        acc += r[(size_t)csr_src[e] * 4 + c];
    out[t] = acc / fmaxf((float)(end - beg), 1.0f) + b2[c] + s[t];
}

extern "C" void kernel_launch(void* const* d_in, const int* in_sizes, int n_in,
                              void* d_out, int out_size, void* d_ws, size_t ws_size,
                              hipStream_t stream)
{
    const float* x   = (const float*)d_in[0];
    const int*   ei  = (const int*)d_in[1];
    const float* W1l = (const float*)d_in[2];
    const float* b1l = (const float*)d_in[3];
    const float* W1r = (const float*)d_in[4];
    const float* W2l = (const float*)d_in[5];
    const float* b2l = (const float*)d_in[6];
    const float* W2r = (const float*)d_in[7];
    float* out = (float*)d_out;

    const int N = in_sizes[0] / 768;   // 50000
    const int E = in_sizes[1] / 2;     // 800000

    char* ws = (char*)d_ws;
    size_t off = 0;
    auto alloc = [&](size_t bytes) -> void* {
        void* pp = ws + off;
        off += (bytes + 255) & ~(size_t)255;
        return pp;
    };
    float* p       = (float*)alloc((size_t)N * 128 * 4);
    float* q       = (float*)alloc((size_t)N * 128 * 4);
    float* h       = (float*)alloc((size_t)N * 128 * 4);
    float* r       = (float*)alloc((size_t)N * 4 * 4);
    float* s       = (float*)alloc((size_t)N * 4 * 4);
    int*   deg     = (int*)alloc((size_t)N * 4);
    int*   row_ptr = (int*)alloc((size_t)(N + 1) * 4);
    int*   cursor  = (int*)alloc((size_t)N * 4);
    int*   csr_src = (int*)alloc((size_t)E * 4);

    // ---- CSR build (independent of GEMMs; stream-ordered)
    hipMemsetAsync(deg, 0, (size_t)N * 4, stream);
    csr_count<<<(E + 255) / 256, 256, 0, stream>>>(ei, deg, E);
    scan_deg<<<1, 1024, 0, stream>>>(deg, row_ptr, cursor, N);
    csr_fill<<<(E + 255) / 256, 256, 0, stream>>>(ei, cursor, csr_src, E);

    // ---- layer 1 projections: p = x@W1l^T, q = x@W1r^T  (M=N, N=128, K=768)
    dim3 g1((N + 63) / 64, 128 / 64);
    gemm_nt<64, 64, 32><<<g1, 256, 0, stream>>>(x, W1l, p, N, 128, 768);
    gemm_nt<64, 64, 32><<<g1, 256, 0, stream>>>(x, W1r, q, N, 128, 768);

    // ---- layer 1 aggregate + epilogue (fused)
    sage1_gather<<<(N + 3) / 4, 256, 0, stream>>>(row_ptr, csr_src, p, q, b1l, h, N);

    // ---- layer 2 projections
    proj2<<<(N + 3) / 4, 256, 0, stream>>>(h, W2l, W2r, r, s, N);

    // ---- layer 2 aggregate + epilogue (fused)
    sage2_gather<<<(N * 4 + 255) / 256, 256, 0, stream>>>(row_ptr, csr_src, r, s, b2l, out, N);
}

// Round 3
// 306.881 us; speedup vs baseline: 5.8515x; 2.0313x over previous
//
#include <hip/hip_runtime.h>

// ---------------------------------------------------------------------------
// TextGraphSAGE: 2-layer SAGEConv (mean aggr), N=50000, D=768, H=128, C=4,
// E=800000.
//  - project BEFORE aggregating (mean commutes with linear map)
//  - CSR gather instead of scatter atomics (r1: 102M float atomics = 77%)
//  - r2: fuse the two layer-1 projections into ONE bf16 MFMA GEMM
//    (x read once, matrix pipe instead of VALU); 3-kernel scan replaces
//    the single-block scan.
// ---------------------------------------------------------------------------

typedef __bf16 bf16x8 __attribute__((ext_vector_type(8)));
typedef float  f32x4  __attribute__((ext_vector_type(4)));

// ---- W pack: Wb[256][768] bf16 = concat(W1l, W1r) rows
__global__ __launch_bounds__(256)
void convert_w(const float* __restrict__ W1l, const float* __restrict__ W1r,
               __bf16* __restrict__ Wb)
{
    int i = blockIdx.x * 256 + threadIdx.x;
    if (i >= 256 * 768) return;
    int n = i / 768, k = i - n * 768;
    float v = (n < 128) ? W1l[n * 768 + k] : W1r[(n - 128) * 768 + k];
    Wb[i] = (__bf16)v;
}

// ---- fused layer-1 projection: pq[M][256] = x[M][768] @ Wb[256][768]^T
// bf16 MFMA 16x16x32, 128x128 tile, 4 waves (2x2), fp32->bf16 in A staging.
__global__ __launch_bounds__(256)
void gemm_bf16(const float* __restrict__ A, const __bf16* __restrict__ Bw,
               float* __restrict__ C, int M)
{
    constexpr int BM = 128, BK = 64, LDK = 72;  // +8 bf16 pad: 2-way LDS max
    __shared__ __bf16 As[BM][LDK];
    __shared__ __bf16 Bs[128][LDK];
    const int bm   = blockIdx.x * BM;
    const int bn   = blockIdx.y * 128;
    const int tid  = threadIdx.x;
    const int lane = tid & 63;
    const int wave = tid >> 6;
    const int wr = wave >> 1, wc = wave & 1;   // 2x2 wave grid, 64x64 each
    const int l15 = lane & 15;
    const int lk  = lane >> 4;                 // 0..3

    f32x4 acc[4][4] = {};

    for (int k0 = 0; k0 < 768; k0 += BK) {
        // stage A: 128 rows x 64 fp32 -> bf16   (1024 x 16B-out ops)
        #pragma unroll
        for (int it = 0; it < 4; ++it) {
            int v   = it * 256 + tid;
            int row = v >> 3;
            int kc  = (v & 7) << 3;
            float4 f0 = make_float4(0.f, 0.f, 0.f, 0.f), f1 = f0;
            if (bm + row < M) {
                const float* src = A + (size_t)(bm + row) * 768 + k0 + kc;
                f0 = *(const float4*)src;
                f1 = *(const float4*)(src + 4);
            }
            bf16x8 b;
            b[0] = (__bf16)f0.x; b[1] = (__bf16)f0.y;
            b[2] = (__bf16)f0.z; b[3] = (__bf16)f0.w;
            b[4] = (__bf16)f1.x; b[5] = (__bf16)f1.y;
            b[6] = (__bf16)f1.z; b[7] = (__bf16)f1.w;
            *(bf16x8*)&As[row][kc] = b;
        }
        // stage B: 128 rows x 64 bf16 (pre-converted)
        #pragma unroll
        for (int it = 0; it < 2; ++it) {
            int v   = it * 256 + tid;
            int row = v >> 2;
            int kc  = (v & 3) << 4;
            bf16x8 b0 = *(const bf16x8*)(Bw + (size_t)(bn + row) * 768 + k0 + kc);
            bf16x8 b1 = *(const bf16x8*)(Bw + (size_t)(bn + row) * 768 + k0 + kc + 8);
            *(bf16x8*)&Bs[row][kc]     = b0;
            *(bf16x8*)&Bs[row][kc + 8] = b1;
        }
        __syncthreads();

        #pragma unroll
        for (int ks = 0; ks < 2; ++ks) {       // two K=32 sub-steps
            int koff = ks * 32 + lk * 8;
            bf16x8 af[4], bfr[4];
            #pragma unroll
            for (int i = 0; i < 4; ++i)
                af[i] = *(const bf16x8*)&As[wr * 64 + i * 16 + l15][koff];
            #pragma unroll
            for (int j = 0; j < 4; ++j)
                bfr[j] = *(const bf16x8*)&Bs[wc * 64 + j * 16 + l15][koff];
            #pragma unroll
            for (int i = 0; i < 4; ++i)
                #pragma unroll
                for (int j = 0; j < 4; ++j)
                    acc[i][j] = __builtin_amdgcn_mfma_f32_16x16x32_bf16(
                        af[i], bfr[j], acc[i][j], 0, 0, 0);
        }
        __syncthreads();
    }

    // C/D layout: col = lane&15, row = (lane>>4)*4 + reg  [m89-verified]
    #pragma unroll
    for (int i = 0; i < 4; ++i) {
        #pragma unroll
        for (int j = 0; j < 4; ++j) {
            #pragma unroll
            for (int v = 0; v < 4; ++v) {
                int row = bm + wr * 64 + i * 16 + lk * 4 + v;
                int col = bn + wc * 64 + j * 16 + l15;
                if (row < M) C[(size_t)row * 256 + col] = acc[i][j][v];
            }
        }
    }
}

// ---- CSR build step 1: degree histogram
__global__ __launch_bounds__(256)
void csr_count(const int* __restrict__ ei, int* __restrict__ deg, int E)
{
    int e = blockIdx.x * 256 + threadIdx.x;
    if (e >= E) return;
    atomicAdd(&deg[ei[E + e]], 1);
}

// ---- scan step 1: per-1024-block exclusive scan + block totals
__global__ __launch_bounds__(1024)
void scan1(const int* __restrict__ deg, int* __restrict__ row_ptr,
           int* __restrict__ partials, int N)
{
    __shared__ int buf[1024];
    int i = blockIdx.x * 1024 + threadIdx.x;
    int v = (i < N) ? deg[i] : 0;
    int val = v;
    buf[threadIdx.x] = val;
    __syncthreads();
    for (int off = 1; off < 1024; off <<= 1) {
        int t = (threadIdx.x >= (unsigned)off) ? buf[threadIdx.x - off] : 0;
        __syncthreads();
        val += t;
        buf[threadIdx.x] = val;
        __syncthreads();
    }
    if (i < N) row_ptr[i] = val - v;            // block-local exclusive
    if (threadIdx.x == 1023) partials[blockIdx.x] = val;
}

// ---- scan step 2: exclusive scan of <=64 block totals (one wave)
__global__ __launch_bounds__(64)
void scan2(int* __restrict__ partials, int nb, int* __restrict__ row_ptr,
           int N, int E)
{
    int lane = threadIdx.x;
    int v = (lane < nb) ? partials[lane] : 0;
    int s = v;
    #pragma unroll
    for (int off = 1; off < 64; off <<= 1) {
        int t = __shfl_up(s, off);
        if (lane >= off) s += t;
    }
    if (lane < nb) partials[lane] = s - v;
    if (lane == 0) row_ptr[N] = E;
}

// ---- scan step 3: add block offsets, init cursors
__global__ __launch_bounds__(1024)
void scan3(int* __restrict__ row_ptr, int* __restrict__ cursor,
           const int* __restrict__ partials, int N)
{
    int i = blockIdx.x * 1024 + threadIdx.x;
    if (i >= N) return;
    int v = row_ptr[i] + partials[blockIdx.x];
    row_ptr[i] = v;
    cursor[i]  = v;
}

// ---- CSR build step 3: scatter src ids into per-dst slots
__global__ __launch_bounds__(256)
void csr_fill(const int* __restrict__ ei, int* __restrict__ cursor,
              int* __restrict__ csr_src, int E)
{
    int e = blockIdx.x * 256 + threadIdx.x;
    if (e >= E) return;
    int src = ei[e];
    int dst = ei[E + e];
    int pos = atomicAdd(&cursor[dst], 1);
    csr_src[pos] = src;
}

// ---- layer 1: h[n] = relu(mean_{src in N(n)} p[src] + b1 + q[n])
// pq[n][0..127] = p, pq[n][128..255] = q. One wave/node, lane owns 2 feats.
__global__ __launch_bounds__(256)
void sage1_gather(const int* __restrict__ row_ptr, const int* __restrict__ csr_src,
                  const float* __restrict__ pq, const float* __restrict__ b1,
                  float* __restrict__ h, int N)
{
    int wid  = threadIdx.x >> 6;
    int lane = threadIdx.x & 63;
    int n = blockIdx.x * 4 + wid;
    if (n >= N) return;
    int beg = row_ptr[n], end = row_ptr[n + 1];
    float ax = 0.f, ay = 0.f;
    for (int e = beg; e < end; ++e) {
        int src = csr_src[e];
        float2 v = *(const float2*)(pq + (size_t)src * 256 + lane * 2);
        ax += v.x; ay += v.y;
    }
    float inv = 1.0f / fmaxf((float)(end - beg), 1.0f);
    float2 qv = *(const float2*)(pq + (size_t)n * 256 + 128 + lane * 2);
    float2 bv = *(const float2*)(b1 + lane * 2);
    float2 hv;
    hv.x = fmaxf(ax * inv + bv.x + qv.x, 0.f);
    hv.y = fmaxf(ay * inv + bv.y + qv.y, 0.f);
    *(float2*)(h + (size_t)n * 128 + lane * 2) = hv;
}

// ---- layer-2 projection: r = h@W2l^T, s = h@W2r^T  (one wave per node)
__global__ __launch_bounds__(256)
void proj2(const float* __restrict__ h, const float* __restrict__ W2l,
           const float* __restrict__ W2r, float* __restrict__ r,
           float* __restrict__ s, int N)
{
    __shared__ float Wl[512], Wr[512];
    for (int i = threadIdx.x; i < 512; i += 256) {
        Wl[i] = W2l[i];
        Wr[i] = W2r[i];
    }
    __syncthreads();
    int wid  = threadIdx.x >> 6;
    int lane = threadIdx.x & 63;
    int n = blockIdx.x * 4 + wid;
    if (n >= N) return;
    float2 hv = *(const float2*)(h + (size_t)n * 128 + lane * 2);
    #pragma unroll
    for (int o = 0; o < 4; ++o) {
        float pl = hv.x * Wl[o * 128 + lane * 2] + hv.y * Wl[o * 128 + lane * 2 + 1];
        float pr = hv.x * Wr[o * 128 + lane * 2] + hv.y * Wr[o * 128 + lane * 2 + 1];
        #pragma unroll
        for (int off = 32; off; off >>= 1) {
            pl += __shfl_down(pl, off);
            pr += __shfl_down(pr, off);
        }
        if (lane == 0) {
            r[(size_t)n * 4 + o] = pl;
            s[(size_t)n * 4 + o] = pr;
        }
    }
}

// ---- layer 2: out[n] = mean_{src} r[src] + b2 + s[n]
__global__ __launch_bounds__(256)
void sage2_gather(const int* __restrict__ row_ptr, const int* __restrict__ csr_src,
                  const float* __restrict__ r, const float* __restrict__ s,
                  const float* __restrict__ b2, float* __restrict__ out, int N)
{
    int t = blockIdx.x * 256 + threadIdx.x;
    if (t >= N * 4) return;
    int n = t >> 2, c = t & 3;
    int beg = row_ptr[n], end = row_ptr[n + 1];
    float acc = 0.f;
    for (int e = beg; e < end; ++e)
        acc += r[(size_t)csr_src[e] * 4 + c];
    out[t] = acc / fmaxf((float)(end - beg), 1.0f) + b2[c] + s[t];
}

extern "C" void kernel_launch(void* const* d_in, const int* in_sizes, int n_in,
                              void* d_out, int out_size, void* d_ws, size_t ws_size,
                              hipStream_t stream)
{
    const float* x   = (const float*)d_in[0];
    const int*   ei  = (const int*)d_in[1];
    const float* W1l = (const float*)d_in[2];
    const float* b1l = (const float*)d_in[3];
    const float* W1r = (const float*)d_in[4];
    const float* W2l = (const float*)d_in[5];
    const float* b2l = (const float*)d_in[6];
    const float* W2r = (const float*)d_in[7];
    float* out = (float*)d_out;

    const int N = in_sizes[0] / 768;   // 50000
    const int E = in_sizes[1] / 2;     // 800000
    const int NB = (N + 1023) / 1024;  // 49 scan blocks

    char* ws = (char*)d_ws;
    size_t off = 0;
    auto alloc = [&](size_t bytes) -> void* {
        void* pp = ws + off;
        off += (bytes + 255) & ~(size_t)255;
        return pp;
    };
    float*  pq      = (float*)alloc((size_t)N * 256 * 4);
    float*  h       = (float*)alloc((size_t)N * 128 * 4);
    float*  r       = (float*)alloc((size_t)N * 4 * 4);
    float*  s       = (float*)alloc((size_t)N * 4 * 4);
    __bf16* Wb      = (__bf16*)alloc((size_t)256 * 768 * 2);
    int*    deg     = (int*)alloc((size_t)N * 4);
    int*    row_ptr = (int*)alloc((size_t)(N + 1) * 4);
    int*    cursor  = (int*)alloc((size_t)N * 4);
    int*    csr_src = (int*)alloc((size_t)E * 4);
    int*    partials= (int*)alloc((size_t)64 * 4);

    // ---- fused layer-1 projection (bf16 MFMA): pq = x @ [W1l;W1r]^T
    convert_w<<<(256 * 768 + 255) / 256, 256, 0, stream>>>(W1l, W1r, Wb);
    dim3 gg((N + 127) / 128, 2);
    gemm_bf16<<<gg, 256, 0, stream>>>(x, Wb, pq, N);

    // ---- CSR build
    hipMemsetAsync(deg, 0, (size_t)N * 4, stream);
    csr_count<<<(E + 255) / 256, 256, 0, stream>>>(ei, deg, E);
    scan1<<<NB, 1024, 0, stream>>>(deg, row_ptr, partials, N);
    scan2<<<1, 64, 0, stream>>>(partials, NB, row_ptr, N, E);
    scan3<<<NB, 1024, 0, stream>>>(row_ptr, cursor, partials, N);
    csr_fill<<<(E + 255) / 256, 256, 0, stream>>>(ei, cursor, csr_src, E);

    // ---- layer 1 aggregate + epilogue (fused)
    sage1_gather<<<(N + 3) / 4, 256, 0, stream>>>(row_ptr, csr_src, pq, b1l, h, N);

    // ---- layer 2
    proj2<<<(N + 3) / 4, 256, 0, stream>>>(h, W2l, W2r, r, s, N);
    sage2_gather<<<(N * 4 + 255) / 256, 256, 0, stream>>>(row_ptr, csr_src, r, s, b2l, out, N);
}

// Round 4
// 231.064 us; speedup vs baseline: 7.7716x; 1.3281x over previous
//
#include <hip/hip_runtime.h>

// ---------------------------------------------------------------------------
// TextGraphSAGE: 2-layer SAGEConv (mean aggr), N=50000, D=768, H=128, C=4,
// E=800000.
//  - project BEFORE aggregating (mean commutes with linear map)
//  - CSR gather instead of scatter atomics (r1: 102M float atomics = 77%)
//  - r2: fused bf16-MFMA projection GEMM (x read once)
//  - r3 profile: gemm latency-bound (Occ 25%, MfmaUtil 7%, HBM 25%).
//    r4: smaller tile (more blocks), reg-prefetch pipeline, bf16 pq output,
//    proj2 fused into the gather (h never hits memory).
// ---------------------------------------------------------------------------

typedef __bf16 bf16x8 __attribute__((ext_vector_type(8)));
typedef float  f32x4  __attribute__((ext_vector_type(4)));

__device__ __forceinline__ float bf16_lo(uint32_t w) {
    union { uint32_t u; float f; } c; c.u = w << 16; return c.f;
}
__device__ __forceinline__ float bf16_hi(uint32_t w) {
    union { uint32_t u; float f; } c; c.u = w & 0xffff0000u; return c.f;
}

// ---- W pack: Wb[256][768] bf16 = concat(W1l, W1r) rows
__global__ __launch_bounds__(256)
void convert_w(const float* __restrict__ W1l, const float* __restrict__ W1r,
               __bf16* __restrict__ Wb)
{
    int i = blockIdx.x * 256 + threadIdx.x;
    if (i >= 256 * 768) return;
    int n = i / 768, k = i - n * 768;
    float v = (n < 128) ? W1l[n * 768 + k] : W1r[(n - 128) * 768 + k];
    Wb[i] = (__bf16)v;
}

// ---- fused layer-1 projection: pq[M][256](bf16) = x[M][768] @ Wb[256][768]^T
// 64x128 tile, 4 waves (2x2), reg-prefetch pipeline, fp32->bf16 in staging.
__global__ __launch_bounds__(256)
void gemm_bf16(const float* __restrict__ A, const __bf16* __restrict__ Bw,
               __bf16* __restrict__ Cb, int M)
{
    constexpr int LDK = 72;                  // +8 bf16 pad (144B row stride)
    __shared__ __bf16 As[64][LDK];           //  9.2 KB
    __shared__ __bf16 Bs[128][LDK];          // 18.4 KB
    const int bm   = blockIdx.x * 64;
    const int bn   = blockIdx.y * 128;
    const int tid  = threadIdx.x;
    const int lane = tid & 63;
    const int wave = tid >> 6;
    const int wr = wave >> 1, wc = wave & 1; // wave tile: 32 rows x 64 cols
    const int l15 = lane & 15;
    const int lk  = lane >> 4;               // 0..3

    f32x4 acc[2][4] = {};
    float4 apref[2][2];
    bf16x8 bpref[4];

    auto load_tile = [&](int k0) {
        #pragma unroll
        for (int it = 0; it < 2; ++it) {
            int v = it * 256 + tid;
            int row = v >> 3, kc = (v & 7) << 3;
            if (bm + row < M) {
                const float* src = A + (size_t)(bm + row) * 768 + k0 + kc;
                apref[it][0] = *(const float4*)src;
                apref[it][1] = *(const float4*)(src + 4);
            } else {
                apref[it][0] = make_float4(0.f, 0.f, 0.f, 0.f);
                apref[it][1] = make_float4(0.f, 0.f, 0.f, 0.f);
            }
        }
        #pragma unroll
        for (int it = 0; it < 4; ++it) {
            int v = it * 256 + tid;
            int row = v >> 3, kc = (v & 7) << 3;
            bpref[it] = *(const bf16x8*)(Bw + (size_t)(bn + row) * 768 + k0 + kc);
        }
    };

    load_tile(0);
    for (int kt = 0; kt < 12; ++kt) {
        if (kt) __syncthreads();             // MFMA of kt-1 done with LDS
        #pragma unroll
        for (int it = 0; it < 2; ++it) {     // A: convert + store
            int v = it * 256 + tid;
            int row = v >> 3, kc = (v & 7) << 3;
            float4 f0 = apref[it][0], f1 = apref[it][1];
            bf16x8 b;
            b[0] = (__bf16)f0.x; b[1] = (__bf16)f0.y;
            b[2] = (__bf16)f0.z; b[3] = (__bf16)f0.w;
            b[4] = (__bf16)f1.x; b[5] = (__bf16)f1.y;
            b[6] = (__bf16)f1.z; b[7] = (__bf16)f1.w;
            *(bf16x8*)&As[row][kc] = b;
        }
        #pragma unroll
        for (int it = 0; it < 4; ++it) {     // B: store
            int v = it * 256 + tid;
            int row = v >> 3, kc = (v & 7) << 3;
            *(bf16x8*)&Bs[row][kc] = bpref[it];
        }
        __syncthreads();
        if (kt < 11) load_tile((kt + 1) * 64);   // in flight across MFMA

        #pragma unroll
        for (int ks = 0; ks < 2; ++ks) {
            int koff = ks * 32 + lk * 8;
            bf16x8 af[2], bfr[4];
            #pragma unroll
            for (int i = 0; i < 2; ++i)
                af[i] = *(const bf16x8*)&As[wr * 32 + i * 16 + l15][koff];
            #pragma unroll
            for (int j = 0; j < 4; ++j)
                bfr[j] = *(const bf16x8*)&Bs[wc * 64 + j * 16 + l15][koff];
            #pragma unroll
            for (int i = 0; i < 2; ++i)
                #pragma unroll
                for (int j = 0; j < 4; ++j)
                    acc[i][j] = __builtin_amdgcn_mfma_f32_16x16x32_bf16(
                        af[i], bfr[j], acc[i][j], 0, 0, 0);
        }
    }

    // C/D layout: col = lane&15, row = (lane>>4)*4 + reg  [m89-verified]
    #pragma unroll
    for (int i = 0; i < 2; ++i)
        #pragma unroll
        for (int j = 0; j < 4; ++j)
            #pragma unroll
            for (int v = 0; v < 4; ++v) {
                int row = bm + wr * 32 + i * 16 + lk * 4 + v;
                int col = bn + wc * 64 + j * 16 + l15;
                if (row < M) Cb[(size_t)row * 256 + col] = (__bf16)acc[i][j][v];
            }
}

// ---- CSR build step 1: degree histogram
__global__ __launch_bounds__(256)
void csr_count(const int* __restrict__ ei, int* __restrict__ deg, int E)
{
    int e = blockIdx.x * 256 + threadIdx.x;
    if (e >= E) return;
    atomicAdd(&deg[ei[E + e]], 1);
}

// ---- scan step 1: per-1024-block exclusive scan + block totals
__global__ __launch_bounds__(1024)
void scan1(const int* __restrict__ deg, int* __restrict__ row_ptr,
           int* __restrict__ partials, int N)
{
    __shared__ int buf[1024];
    int i = blockIdx.x * 1024 + threadIdx.x;
    int v = (i < N) ? deg[i] : 0;
    int val = v;
    buf[threadIdx.x] = val;
    __syncthreads();
    for (int off = 1; off < 1024; off <<= 1) {
        int t = (threadIdx.x >= (unsigned)off) ? buf[threadIdx.x - off] : 0;
        __syncthreads();
        val += t;
        buf[threadIdx.x] = val;
        __syncthreads();
    }
    if (i < N) row_ptr[i] = val - v;
    if (threadIdx.x == 1023) partials[blockIdx.x] = val;
}

// ---- scan step 2: exclusive scan of <=64 block totals (one wave)
__global__ __launch_bounds__(64)
void scan2(int* __restrict__ partials, int nb, int* __restrict__ row_ptr,
           int N, int E)
{
    int lane = threadIdx.x;
    int v = (lane < nb) ? partials[lane] : 0;
    int s = v;
    #pragma unroll
    for (int off = 1; off < 64; off <<= 1) {
        int t = __shfl_up(s, off);
        if (lane >= off) s += t;
    }
    if (lane < nb) partials[lane] = s - v;
    if (lane == 0) row_ptr[N] = E;
}

// ---- scan step 3: add block offsets, init cursors
__global__ __launch_bounds__(1024)
void scan3(int* __restrict__ row_ptr, int* __restrict__ cursor,
           const int* __restrict__ partials, int N)
{
    int i = blockIdx.x * 1024 + threadIdx.x;
    if (i >= N) return;
    int v = row_ptr[i] + partials[blockIdx.x];
    row_ptr[i] = v;
    cursor[i]  = v;
}

// ---- CSR build step 3: scatter src ids into per-dst slots
__global__ __launch_bounds__(256)
void csr_fill(const int* __restrict__ ei, int* __restrict__ cursor,
              int* __restrict__ csr_src, int E)
{
    int e = blockIdx.x * 256 + threadIdx.x;
    if (e >= E) return;
    int src = ei[e];
    int dst = ei[E + e];
    int pos = atomicAdd(&cursor[dst], 1);
    csr_src[pos] = src;
}

// ---- layer 1 + layer-2 projection, fused. One wave per node.
// h[n] = relu(mean_{src} p[src] + b1 + q[n]) computed in registers,
// then r[n] = h@W2l^T, s[n] = h@W2r^T via butterfly reduction.
__global__ __launch_bounds__(256)
void sage1_fused(const int* __restrict__ row_ptr, const int* __restrict__ csr_src,
                 const __bf16* __restrict__ pq, const float* __restrict__ b1,
                 const float* __restrict__ W2l, const float* __restrict__ W2r,
                 float* __restrict__ r, float* __restrict__ s, int N)
{
    __shared__ float Wl[512], Wr[512];
    for (int i = threadIdx.x; i < 512; i += 256) {
        Wl[i] = W2l[i];
        Wr[i] = W2r[i];
    }
    __syncthreads();

    int wid  = threadIdx.x >> 6;
    int lane = threadIdx.x & 63;
    int n = blockIdx.x * 4 + wid;
    if (n >= N) return;
    int beg = row_ptr[n], end = row_ptr[n + 1];

    float ax = 0.f, ay = 0.f;
    for (int eb = beg; eb < end; eb += 64) {
        int cnt = min(64, end - eb);
        int id = (eb + lane < end) ? csr_src[eb + lane] : 0;
        for (int t = 0; t < cnt; ++t) {
            int src = __shfl(id, t);
            uint32_t w = *(const uint32_t*)(pq + (size_t)src * 256 + lane * 2);
            ax += bf16_lo(w);
            ay += bf16_hi(w);
        }
    }
    float inv = 1.0f / fmaxf((float)(end - beg), 1.0f);
    uint32_t qw = *(const uint32_t*)(pq + (size_t)n * 256 + 128 + lane * 2);
    float hx = fmaxf(ax * inv + b1[2 * lane]     + bf16_lo(qw), 0.f);
    float hy = fmaxf(ay * inv + b1[2 * lane + 1] + bf16_hi(qw), 0.f);

    // proj2 inline: 8 dot-products of length 128 across the wave
    float part[8];
    #pragma unroll
    for (int c = 0; c < 4; ++c) {
        part[c]     = hx * Wl[c * 128 + 2 * lane] + hy * Wl[c * 128 + 2 * lane + 1];
        part[4 + c] = hx * Wr[c * 128 + 2 * lane] + hy * Wr[c * 128 + 2 * lane + 1];
    }
    #pragma unroll
    for (int off = 32; off; off >>= 1)
        #pragma unroll
        for (int c = 0; c < 8; ++c)
            part[c] += __shfl_xor(part[c], off);
    if (lane == 0) {
        *(float4*)(r + (size_t)n * 4) = make_float4(part[0], part[1], part[2], part[3]);
        *(float4*)(s + (size_t)n * 4) = make_float4(part[4], part[5], part[6], part[7]);
    }
}

// ---- layer 2: out[n] = mean_{src} r[src] + b2 + s[n]
__global__ __launch_bounds__(256)
void sage2_gather(const int* __restrict__ row_ptr, const int* __restrict__ csr_src,
                  const float* __restrict__ r, const float* __restrict__ s,
                  const float* __restrict__ b2, float* __restrict__ out, int N)
{
    int t = blockIdx.x * 256 + threadIdx.x;
    if (t >= N * 4) return;
    int n = t >> 2, c = t & 3;
    int beg = row_ptr[n], end = row_ptr[n + 1];
    float acc = 0.f;
    for (int e = beg; e < end; ++e)
        acc += r[(size_t)csr_src[e] * 4 + c];
    out[t] = acc / fmaxf((float)(end - beg), 1.0f) + b2[c] + s[t];
}

extern "C" void kernel_launch(void* const* d_in, const int* in_sizes, int n_in,
                              void* d_out, int out_size, void* d_ws, size_t ws_size,
                              hipStream_t stream)
{
    const float* x   = (const float*)d_in[0];
    const int*   ei  = (const int*)d_in[1];
    const float* W1l = (const float*)d_in[2];
    const float* b1l = (const float*)d_in[3];
    const float* W1r = (const float*)d_in[4];
    const float* W2l = (const float*)d_in[5];
    const float* b2l = (const float*)d_in[6];
    const float* W2r = (const float*)d_in[7];
    float* out = (float*)d_out;

    const int N = in_sizes[0] / 768;   // 50000
    const int E = in_sizes[1] / 2;     // 800000
    const int NB = (N + 1023) / 1024;  // 49 scan blocks

    char* ws = (char*)d_ws;
    size_t off = 0;
    auto alloc = [&](size_t bytes) -> void* {
        void* pp = ws + off;
        off += (bytes + 255) & ~(size_t)255;
        return pp;
    };
    __bf16* pq      = (__bf16*)alloc((size_t)N * 256 * 2);
    float*  r       = (float*)alloc((size_t)N * 4 * 4);
    float*  s       = (float*)alloc((size_t)N * 4 * 4);
    __bf16* Wb      = (__bf16*)alloc((size_t)256 * 768 * 2);
    int*    deg     = (int*)alloc((size_t)N * 4);
    int*    row_ptr = (int*)alloc((size_t)(N + 1) * 4);
    int*    cursor  = (int*)alloc((size_t)N * 4);
    int*    csr_src = (int*)alloc((size_t)E * 4);
    int*    partials= (int*)alloc((size_t)64 * 4);

    // ---- fused layer-1 projection (bf16 MFMA): pq = x @ [W1l;W1r]^T
    convert_w<<<(256 * 768 + 255) / 256, 256, 0, stream>>>(W1l, W1r, Wb);
    dim3 gg((N + 63) / 64, 2);
    gemm_bf16<<<gg, 256, 0, stream>>>(x, Wb, pq, N);

    // ---- CSR build
    hipMemsetAsync(deg, 0, (size_t)N * 4, stream);
    csr_count<<<(E + 255) / 256, 256, 0, stream>>>(ei, deg, E);
    scan1<<<NB, 1024, 0, stream>>>(deg, row_ptr, partials, N);
    scan2<<<1, 64, 0, stream>>>(partials, NB, row_ptr, N, E);
    scan3<<<NB, 1024, 0, stream>>>(row_ptr, cursor, partials, N);
    csr_fill<<<(E + 255) / 256, 256, 0, stream>>>(ei, cursor, csr_src, E);

    // ---- layer 1 aggregate + epilogue + layer-2 projection (fused)
    sage1_fused<<<(N + 3) / 4, 256, 0, stream>>>(row_ptr, csr_src, pq, b1l,
                                                 W2l, W2r, r, s, N);

    // ---- layer 2 aggregate + epilogue
    sage2_gather<<<(N * 4 + 255) / 256, 256, 0, stream>>>(row_ptr, csr_src, r, s, b2l, out, N);
}